// Round 1
// baseline (688.170 us; speedup 1.0000x reference)
//
#include <hip/hip_runtime.h>
#include <math.h>

#define S_LEN 2048
#define DK 64
#define NW 128

__global__ __launch_bounds__(256) void band_attn_kernel(
    const float* __restrict__ Q,
    const float* __restrict__ K,
    const float* __restrict__ V,
    float* __restrict__ ctx_out,   // [BH*S, DK]
    float* __restrict__ attn_out)  // [BH*S, S]
{
    const int row = blockIdx.x;          // 0 .. BH*S-1
    const int i   = row & (S_LEN - 1);   // query position
    const int bh  = row >> 11;           // head index (S=2048 -> shift 11)
    const int tid = threadIdx.x;

    __shared__ float qs[DK];
    __shared__ float ps[256];            // probabilities, len <= 255
    __shared__ float red[4];             // per-wave partials
    __shared__ float ctxp[4][DK];        // context partials per key-chunk

    const int lo  = max(0, i - (NW - 1));
    const int hi  = min(S_LEN, i + NW);
    const int len = hi - lo;             // 128..255

    // ---- Q row -> LDS, pre-scaled by 1/sqrt(64) ----
    if (tid < DK) qs[tid] = Q[(size_t)row * DK + tid] * 0.125f;
    __syncthreads();

    // ---- scores: one key per thread ----
    float s = -INFINITY;
    if (tid < len) {
        const float4* krow = (const float4*)(K + ((size_t)bh * S_LEN + lo + tid) * DK);
        const float4* q4   = (const float4*)qs;
        float acc = 0.f;
        #pragma unroll
        for (int j = 0; j < DK / 4; ++j) {
            float4 k4 = krow[j];
            float4 qq = q4[j];   // LDS broadcast (same addr across wave)
            acc += qq.x * k4.x + qq.y * k4.y + qq.z * k4.z + qq.w * k4.w;
        }
        s = acc;
    }

    const int wave = tid >> 6;
    const int lane = tid & 63;

    // ---- block max ----
    float m = s;
    #pragma unroll
    for (int off = 32; off > 0; off >>= 1)
        m = fmaxf(m, __shfl_down(m, off, 64));
    if (lane == 0) red[wave] = m;
    __syncthreads();
    const float bm = fmaxf(fmaxf(red[0], red[1]), fmaxf(red[2], red[3]));
    __syncthreads();   // red reads done before reuse

    // ---- exp + block sum ----
    float p = (tid < len) ? __expf(s - bm) : 0.f;
    float sum = p;
    #pragma unroll
    for (int off = 32; off > 0; off >>= 1)
        sum += __shfl_down(sum, off, 64);
    if (lane == 0) red[wave] = sum;
    __syncthreads();
    const float inv = 1.0f / (red[0] + red[1] + red[2] + red[3]);
    p *= inv;
    ps[tid] = p;       // threads >= len store exact 0
    __syncthreads();

    // ---- write full attn row (band + zeros), coalesced float4 ----
    float4* arow = (float4*)(attn_out + (size_t)row * S_LEN);
    #pragma unroll
    for (int k = 0; k < S_LEN / (256 * 4); ++k) {   // 2 iterations
        const int q4i = tid + k * 256;
        const int j0  = q4i * 4;
        float4 v;
        v.x = (j0 + 0 >= lo && j0 + 0 < hi) ? ps[j0 + 0 - lo] : 0.f;
        v.y = (j0 + 1 >= lo && j0 + 1 < hi) ? ps[j0 + 1 - lo] : 0.f;
        v.z = (j0 + 2 >= lo && j0 + 2 < hi) ? ps[j0 + 2 - lo] : 0.f;
        v.w = (j0 + 3 >= lo && j0 + 3 < hi) ? ps[j0 + 3 - lo] : 0.f;
        arow[q4i] = v;
    }

    // ---- context: thread (chunk c, dim d); coalesced V reads ----
    const int c = tid >> 6;   // 0..3
    const int d = tid & 63;
    float acc = 0.f;
    const float* vbase = V + ((size_t)bh * S_LEN + lo) * DK + d;
    for (int t = c; t < len; t += 4)
        acc += ps[t] * vbase[(size_t)t * DK];
    ctxp[c][d] = acc;
    __syncthreads();
    if (tid < DK)
        ctx_out[(size_t)row * DK + tid] =
            ctxp[0][tid] + ctxp[1][tid] + ctxp[2][tid] + ctxp[3][tid];
}

extern "C" void kernel_launch(void* const* d_in, const int* in_sizes, int n_in,
                              void* d_out, int out_size, void* d_ws, size_t ws_size,
                              hipStream_t stream) {
    const float* Q = (const float*)d_in[0];
    const float* K = (const float*)d_in[1];
    const float* V = (const float*)d_in[2];
    float* out = (float*)d_out;

    const int BH = in_sizes[0] / (S_LEN * DK);       // B*H = 16
    const size_t ctx_elems = (size_t)BH * S_LEN * DK;
    float* ctx  = out;                               // context first in tuple
    float* attn = out + ctx_elems;                   // then full attn matrix

    dim3 grid(BH * S_LEN);
    band_attn_kernel<<<grid, 256, 0, stream>>>(Q, K, V, ctx, attn);
}

// Round 2
// 353.023 us; speedup vs baseline: 1.9494x; 1.9494x over previous
//
#include <hip/hip_runtime.h>
#include <math.h>

#define S_LEN 2048
#define DK 64
#define NW 128
#define TQ 32          // queries per block
#define CH 32          // keys per staged chunk
#define NCH 10         // chunks: klocal 0..319
#define KLW 320        // klocal width (NCH*CH)
#define PSTR 324       // Ps stride in floats (324%32==4 -> conflict-free patterns)
#define PSTR4 81
#define SSTR 68        // Qs/St stride in floats (+4 pad)
#define SSTR4 17

#define DOT4(acc, a, b) \
    acc.x = fmaf(a.x, b.x, acc.x); \
    acc.y = fmaf(a.y, b.y, acc.y); \
    acc.z = fmaf(a.z, b.z, acc.z); \
    acc.w = fmaf(a.w, b.w, acc.w);

#define AXPY4(acc, s, v) \
    acc.x = fmaf(s, v.x, acc.x); \
    acc.y = fmaf(s, v.y, acc.y); \
    acc.z = fmaf(s, v.z, acc.z); \
    acc.w = fmaf(s, v.w, acc.w);

__global__ __launch_bounds__(256, 2) void band_attn_tile(
    const float* __restrict__ Q,
    const float* __restrict__ K,
    const float* __restrict__ V,
    float* __restrict__ ctx_out,   // [BH, S, DK]
    float* __restrict__ attn_out)  // [BH, S, S]
{
    __shared__ float Qs[TQ * SSTR];   //  8704 B
    __shared__ float St[CH * SSTR];   //  8704 B (K chunks, then V chunks)
    __shared__ float Ps[TQ * PSTR];   // 41472 B
    // total 58880 B -> 2 blocks/CU

    const int tid  = threadIdx.x;
    const int bh   = blockIdx.x >> 6;          // S/TQ = 64 tiles per head
    const int q0   = (blockIdx.x & 63) * TQ;
    const int base = q0 - (NW - 1);            // klocal kl <-> kg = base + kl

    float4* Qs4 = (float4*)Qs;
    float4* St4 = (float4*)St;
    float4* Ps4 = (float4*)Ps;

    // ---- Q tile -> LDS, pre-scaled by 1/sqrt(64) ----
    {
        const float4* Q4 = (const float4*)(Q + ((size_t)bh * S_LEN + q0) * DK);
        #pragma unroll
        for (int h = 0; h < 2; ++h) {
            int idx = tid + h * 256;           // 512 float4 total
            int r = idx >> 4, c4 = idx & 15;
            float4 v = Q4[r * 16 + c4];
            v.x *= 0.125f; v.y *= 0.125f; v.z *= 0.125f; v.w *= 0.125f;
            Qs4[r * SSTR4 + c4] = v;
        }
    }

    const int q2 = tid >> 4;      // 0..15
    const int kb = tid & 15;      // 0..15 (k strided by 16 -> 2-way LDS, free)
    const int qA = 2 * q2, qB = qA + 1;

    const float4* Kh4 = (const float4*)(K + (size_t)bh * S_LEN * DK);
    const float4* Vh4 = (const float4*)(V + (size_t)bh * S_LEN * DK);

    // ---- score phase: raw scores (or -inf) into Ps ----
    for (int c = 0; c < NCH; ++c) {
        __syncthreads();                       // St free of prior readers (also Qs visibility at c=0)
        #pragma unroll
        for (int h = 0; h < 2; ++h) {
            int idx = tid + h * 256;
            int r = idx >> 4, c4 = idx & 15;
            int kg = base + c * CH + r;
            float4 v = {0.f, 0.f, 0.f, 0.f};
            if (kg >= 0 && kg < S_LEN) v = Kh4[(size_t)kg * 16 + c4];
            St4[r * SSTR4 + c4] = v;
        }
        __syncthreads();

        float4 a00 = {0,0,0,0}, a01 = {0,0,0,0}, a10 = {0,0,0,0}, a11 = {0,0,0,0};
        #pragma unroll
        for (int j = 0; j < 16; ++j) {
            float4 qa = Qs4[qA * SSTR4 + j];
            float4 qb = Qs4[qB * SSTR4 + j];
            float4 k0 = St4[kb * SSTR4 + j];
            float4 k1 = St4[(kb + 16) * SSTR4 + j];
            DOT4(a00, qa, k0); DOT4(a01, qa, k1);
            DOT4(a10, qb, k0); DOT4(a11, qb, k1);
        }
        float s00 = (a00.x + a00.y) + (a00.z + a00.w);
        float s01 = (a01.x + a01.y) + (a01.z + a01.w);
        float s10 = (a10.x + a10.y) + (a10.z + a10.w);
        float s11 = (a11.x + a11.y) + (a11.z + a11.w);

        const int klA = c * CH + kb, klB = klA + 16;
        const int kgA = base + klA, kgB = base + klB;
        const bool okA = (kgA >= 0) && (kgA < S_LEN);
        const bool okB = (kgB >= 0) && (kgB < S_LEN);
        // in-band: |q - kg| < 128  <=>  qloc <= kl <= qloc + 254
        Ps[qA * PSTR + klA] = (okA && klA >= qA && klA <= qA + 254) ? s00 : -INFINITY;
        Ps[qA * PSTR + klB] = (okB && klB >= qA && klB <= qA + 254) ? s01 : -INFINITY;
        Ps[qB * PSTR + klA] = (okA && klA >= qB && klA <= qB + 254) ? s10 : -INFINITY;
        Ps[qB * PSTR + klB] = (okB && klB >= qB && klB <= qB + 254) ? s11 : -INFINITY;
    }
    __syncthreads();

    // ---- softmax: wave w owns rows 8w..8w+7 ----
    {
        const int wv = tid >> 6, ln = tid & 63;
        for (int rr = 0; rr < 8; ++rr) {
            const int r = wv * 8 + rr;
            float v[5];
            #pragma unroll
            for (int j = 0; j < 5; ++j) v[j] = Ps[r * PSTR + ln + 64 * j];
            float m = v[0];
            #pragma unroll
            for (int j = 1; j < 5; ++j) m = fmaxf(m, v[j]);
            #pragma unroll
            for (int off = 32; off > 0; off >>= 1) m = fmaxf(m, __shfl_xor(m, off, 64));
            float e[5], sum = 0.f;
            #pragma unroll
            for (int j = 0; j < 5; ++j) { e[j] = __expf(v[j] - m); sum += e[j]; }
            #pragma unroll
            for (int off = 32; off > 0; off >>= 1) sum += __shfl_xor(sum, off, 64);
            const float inv = 1.0f / sum;
            #pragma unroll
            for (int j = 0; j < 5; ++j) Ps[r * PSTR + ln + 64 * j] = e[j] * inv;
        }
    }

    // ---- context: thread (qp, dq) owns q={2qp,2qp+1}, d=4dq..4dq+3 ----
    const int qp = tid >> 4;          // 0..15
    const int dq = tid & 15;          // 0..15
    const int cqA = 2 * qp, cqB = cqA + 1;
    float4 accA = {0,0,0,0}, accB = {0,0,0,0};
    for (int c = 0; c < NCH; ++c) {
        __syncthreads();              // St free of prior readers (also Ps ready at c=0)
        #pragma unroll
        for (int h = 0; h < 2; ++h) {
            int idx = tid + h * 256;
            int r = idx >> 4, c4 = idx & 15;
            int kg = base + c * CH + r;
            float4 v = {0.f, 0.f, 0.f, 0.f};
            if (kg >= 0 && kg < S_LEN) v = Vh4[(size_t)kg * 16 + c4];
            St4[r * SSTR4 + c4] = v;
        }
        __syncthreads();
        #pragma unroll
        for (int t0 = 0; t0 < CH; t0 += 4) {
            const int idx4 = c * 8 + (t0 >> 2);
            float4 pA = Ps4[cqA * PSTR4 + idx4];
            float4 pB = Ps4[cqB * PSTR4 + idx4];
            float4 v0 = St4[(t0 + 0) * SSTR4 + dq];
            float4 v1 = St4[(t0 + 1) * SSTR4 + dq];
            float4 v2 = St4[(t0 + 2) * SSTR4 + dq];
            float4 v3 = St4[(t0 + 3) * SSTR4 + dq];
            AXPY4(accA, pA.x, v0); AXPY4(accA, pA.y, v1);
            AXPY4(accA, pA.z, v2); AXPY4(accA, pA.w, v3);
            AXPY4(accB, pB.x, v0); AXPY4(accB, pB.y, v1);
            AXPY4(accB, pB.z, v2); AXPY4(accB, pB.w, v3);
        }
    }

    // ---- context write ----
    {
        float4* C4 = (float4*)(ctx_out + (size_t)bh * S_LEN * DK);
        C4[(size_t)(q0 + cqA) * 16 + dq] = accA;
        C4[(size_t)(q0 + cqB) * 16 + dq] = accB;
    }

    // ---- attn write: full rows, band from Ps, zeros elsewhere ----
    {
        float4* A4 = (float4*)(attn_out + ((size_t)bh * S_LEN + q0) * S_LEN);
        for (int r = 0; r < TQ; ++r) {
            float4* row4 = A4 + (size_t)r * (S_LEN / 4);
            #pragma unroll
            for (int h = 0; h < 2; ++h) {
                const int idx = tid + h * 256;
                const int b0 = idx * 4 - base;     // klocal of component .x
                float4 v = {0.f, 0.f, 0.f, 0.f};
                if (b0 + 3 >= 0 && b0 < KLW) {
                    const float* pr = Ps + r * PSTR;
                    v.x = ((unsigned)(b0 + 0) < KLW) ? pr[b0 + 0] : 0.f;
                    v.y = ((unsigned)(b0 + 1) < KLW) ? pr[b0 + 1] : 0.f;
                    v.z = ((unsigned)(b0 + 2) < KLW) ? pr[b0 + 2] : 0.f;
                    v.w = ((unsigned)(b0 + 3) < KLW) ? pr[b0 + 3] : 0.f;
                }
                row4[idx] = v;
            }
        }
    }
}

extern "C" void kernel_launch(void* const* d_in, const int* in_sizes, int n_in,
                              void* d_out, int out_size, void* d_ws, size_t ws_size,
                              hipStream_t stream) {
    const float* Q = (const float*)d_in[0];
    const float* K = (const float*)d_in[1];
    const float* V = (const float*)d_in[2];
    float* out = (float*)d_out;

    const int BH = in_sizes[0] / (S_LEN * DK);          // B*H = 16
    const size_t ctx_elems = (size_t)BH * S_LEN * DK;
    float* ctx  = out;
    float* attn = out + ctx_elems;

    dim3 grid(BH * (S_LEN / TQ));                       // 16 * 64 = 1024 blocks
    band_attn_tile<<<grid, 256, 0, stream>>>(Q, K, V, ctx, attn);
}

// Round 3
// 326.380 us; speedup vs baseline: 2.1085x; 1.0816x over previous
//
#include <hip/hip_runtime.h>
#include <math.h>

#define S_LEN 2048
#define DK 64
#define TQ 32          // queries per block
#define KLW 320        // klocal band width
#define CH 64          // keys per staged chunk
#define NCH 5          // chunks
#define PSTR 324       // Ps row stride (floats); 324%32w=4 -> conflict-free
#define PSTR4 81
#define KSTR 72        // Qs/St row stride (shorts); 144B rows, 16B-aligned frags
#define KSTR4 18

typedef __attribute__((ext_vector_type(8))) short bf16x8;
typedef __attribute__((ext_vector_type(4))) float f32x4;
typedef __attribute__((ext_vector_type(4))) short short4v;

__device__ __forceinline__ short f2bf(float f) {
    unsigned u = __float_as_uint(f);
    unsigned r = (u + 0x7fffu + ((u >> 16) & 1u)) >> 16;   // RNE
    return (short)r;
}

__global__ __launch_bounds__(256, 2) void band_attn_mfma(
    const float* __restrict__ Q,
    const float* __restrict__ K,
    const float* __restrict__ V,
    float* __restrict__ ctx_out,   // [BH, S, DK]
    float* __restrict__ attn_out)  // [BH, S, S]
{
    __shared__ __align__(16) float Ps[TQ * PSTR];   // 41472 B (scores -> probs)
    __shared__ __align__(16) short Qs[TQ * KSTR];   //  4608 B (bf16 Q, pre-scaled)
    __shared__ __align__(16) short St[CH * KSTR];   //  9216 B (bf16 K chunk / V^T chunk)
    // total 55296 B -> 2 blocks/CU

    const int tid  = threadIdx.x;
    const int bh   = blockIdx.x >> 6;            // 64 tiles per head
    const int q0   = (blockIdx.x & 63) * TQ;
    const int base = q0 - 128;                   // kg = base + kl; base % 4 == 0

    const int lane = tid & 63;
    const int wv   = tid >> 6;                   // wave 0..3
    const int col  = lane & 15;
    const int quad = lane >> 4;

    const float4* Qg = (const float4*)(Q + ((size_t)bh * S_LEN + q0) * DK);
    const float4* Kg = (const float4*)(K + (size_t)bh * S_LEN * DK);
    const float4* Vg = (const float4*)(V + (size_t)bh * S_LEN * DK);

    // ---- stage Q tile (bf16, pre-scaled by 1/8) ----
    {
        short4v* Qs4 = (short4v*)Qs;
        #pragma unroll
        for (int h = 0; h < 2; ++h) {
            int idx = tid + h * 256;             // 512 float4
            int r = idx >> 4, c4 = idx & 15;
            float4 v = Qg[r * 16 + c4];
            short4v s = { f2bf(v.x * 0.125f), f2bf(v.y * 0.125f),
                          f2bf(v.z * 0.125f), f2bf(v.w * 0.125f) };
            Qs4[r * KSTR4 + c4] = s;
        }
    }

    // ---- score phase: QK^T via MFMA, masked scores -> Ps ----
    for (int c = 0; c < NCH; ++c) {
        __syncthreads();                         // St free (and Qs visible at c=0)
        {
            short4v* St4 = (short4v*)St;
            #pragma unroll
            for (int h = 0; h < 4; ++h) {
                int idx = tid + h * 256;         // 1024 float4
                int r = idx >> 4, c4 = idx & 15; // key-in-chunk, d-group
                int kg = base + c * CH + r;
                float4 v = {0.f, 0.f, 0.f, 0.f};
                if ((unsigned)kg < S_LEN) v = Kg[(size_t)kg * 16 + c4];
                short4v s = { f2bf(v.x), f2bf(v.y), f2bf(v.z), f2bf(v.w) };
                St4[r * KSTR4 + c4] = s;
            }
        }
        __syncthreads();

        const int kl = c * CH + 16 * wv + col;   // this wave's ktile = 4c + wv
        const int kg = base + kl;
        #pragma unroll
        for (int qt = 0; qt < 2; ++qt) {
            f32x4 acc = {0.f, 0.f, 0.f, 0.f};
            #pragma unroll
            for (int h = 0; h < 2; ++h) {
                bf16x8 a = *(const bf16x8*)(Qs + (16 * qt + col) * KSTR + h * 32 + quad * 8);
                bf16x8 b = *(const bf16x8*)(St + (16 * wv + col) * KSTR + h * 32 + quad * 8);
                acc = __builtin_amdgcn_mfma_f32_16x16x32_bf16(a, b, acc, 0, 0, 0);
            }
            #pragma unroll
            for (int r = 0; r < 4; ++r) {
                int qloc = 16 * qt + quad * 4 + r;       // C/D: row=(l>>4)*4+reg, col=l&15
                bool ok = ((unsigned)kg < S_LEN) && (kl > qloc) && (kl <= qloc + 255);
                Ps[qloc * PSTR + kl] = ok ? acc[r] : -INFINITY;
            }
        }
    }
    __syncthreads();

    // ---- softmax: wave wv owns rows 8wv..8wv+7 (320 = 5*64 values/row) ----
    #pragma unroll
    for (int rr = 0; rr < 8; ++rr) {
        float* row = Ps + (wv * 8 + rr) * PSTR;
        float v[5];
        #pragma unroll
        for (int j = 0; j < 5; ++j) v[j] = row[lane + 64 * j];
        float m = fmaxf(fmaxf(fmaxf(v[0], v[1]), fmaxf(v[2], v[3])), v[4]);
        #pragma unroll
        for (int off = 32; off > 0; off >>= 1) m = fmaxf(m, __shfl_xor(m, off, 64));
        float e[5], sum = 0.f;
        #pragma unroll
        for (int j = 0; j < 5; ++j) { e[j] = __expf(v[j] - m); sum += e[j]; }
        #pragma unroll
        for (int off = 32; off > 0; off >>= 1) sum += __shfl_xor(sum, off, 64);
        const float inv = 1.0f / sum;
        #pragma unroll
        for (int j = 0; j < 5; ++j) row[lane + 64 * j] = e[j] * inv;
    }

    // ---- PV phase: stage V^T chunks, accumulate context via MFMA ----
    f32x4 o0 = {0.f, 0.f, 0.f, 0.f}, o1 = {0.f, 0.f, 0.f, 0.f};
    for (int c = 0; c < NCH; ++c) {
        __syncthreads();                         // St free; (Ps ready at c=0)
        {
            #pragma unroll
            for (int h = 0; h < 4; ++h) {
                int idx = tid + h * 256;
                int r = idx >> 4, c4 = idx & 15; // key-in-chunk, d-group
                int kg = base + c * CH + r;
                float4 v = {0.f, 0.f, 0.f, 0.f};
                if ((unsigned)kg < S_LEN) v = Vg[(size_t)kg * 16 + c4];
                St[(4 * c4 + 0) * KSTR + r] = f2bf(v.x);   // V^T: [d][key]
                St[(4 * c4 + 1) * KSTR + r] = f2bf(v.y);
                St[(4 * c4 + 2) * KSTR + r] = f2bf(v.z);
                St[(4 * c4 + 3) * KSTR + r] = f2bf(v.w);
            }
        }
        __syncthreads();

        #pragma unroll
        for (int h = 0; h < 2; ++h) {
            // B-frag: Vt[d = 16*wv + col][k = c*64 + h*32 + quad*8 + j]
            bf16x8 b = *(const bf16x8*)(St + (16 * wv + col) * KSTR + h * 32 + quad * 8);
            #pragma unroll
            for (int qt = 0; qt < 2; ++qt) {
                const float* pp = Ps + (16 * qt + col) * PSTR + c * CH + h * 32 + quad * 8;
                f32x4 p0 = *(const f32x4*)(pp);
                f32x4 p1 = *(const f32x4*)(pp + 4);
                bf16x8 a = { f2bf(p0[0]), f2bf(p0[1]), f2bf(p0[2]), f2bf(p0[3]),
                             f2bf(p1[0]), f2bf(p1[1]), f2bf(p1[2]), f2bf(p1[3]) };
                if (qt == 0) o0 = __builtin_amdgcn_mfma_f32_16x16x32_bf16(a, b, o0, 0, 0, 0);
                else         o1 = __builtin_amdgcn_mfma_f32_16x16x32_bf16(a, b, o1, 0, 0, 0);
            }
        }
    }

    // ---- context write: tile (qt, dt=wv); d = 16*wv + col, q = 16*qt + quad*4 + r ----
    {
        float* Cg = ctx_out + ((size_t)bh * S_LEN + q0) * DK;
        #pragma unroll
        for (int r = 0; r < 4; ++r) {
            Cg[(size_t)(quad * 4 + r) * DK + 16 * wv + col]        = o0[r];
            Cg[(size_t)(16 + quad * 4 + r) * DK + 16 * wv + col]   = o1[r];
        }
    }

    // ---- attn write: full rows; band float4s are aligned (base % 4 == 0) ----
    {
        f32x4* A4 = (f32x4*)(attn_out + ((size_t)bh * S_LEN + q0) * S_LEN);
        const f32x4* Ps4 = (const f32x4*)Ps;
        const int b0 = 4 * tid - base;           // klocal of this thread's first float4
        const int b1 = b0 + 1024;
        const f32x4 z = {0.f, 0.f, 0.f, 0.f};
        for (int r = 0; r < TQ; ++r) {
            f32x4 va = ((unsigned)b0 < KLW) ? Ps4[r * PSTR4 + (b0 >> 2)] : z;
            f32x4 vb = ((unsigned)b1 < KLW) ? Ps4[r * PSTR4 + (b1 >> 2)] : z;
            A4[(size_t)r * 512 + tid]       = va;
            A4[(size_t)r * 512 + tid + 256] = vb;
        }
    }
}

extern "C" void kernel_launch(void* const* d_in, const int* in_sizes, int n_in,
                              void* d_out, int out_size, void* d_ws, size_t ws_size,
                              hipStream_t stream) {
    const float* Q = (const float*)d_in[0];
    const float* K = (const float*)d_in[1];
    const float* V = (const float*)d_in[2];
    float* out = (float*)d_out;

    const int BH = in_sizes[0] / (S_LEN * DK);          // B*H = 16
    const size_t ctx_elems = (size_t)BH * S_LEN * DK;
    float* ctx  = out;
    float* attn = out + ctx_elems;

    dim3 grid(BH * (S_LEN / TQ));                       // 1024 blocks
    band_attn_mfma<<<grid, 256, 0, stream>>>(Q, K, V, ctx, attn);
}

// Round 4
// 303.791 us; speedup vs baseline: 2.2653x; 1.0744x over previous
//
#include <hip/hip_runtime.h>
#include <math.h>

#define S_LEN 2048
#define DK 64
#define TQ 32          // queries per block
#define KLW 320        // klocal band width
#define NCH 5          // 5 chunks of 64 keys
#define PSTR 324       // Ps row stride (floats); %32==4 -> conflict-free
#define PSTR4 81

typedef __attribute__((ext_vector_type(8))) short bf16x8;
typedef __attribute__((ext_vector_type(4))) float f32x4;

__device__ __forceinline__ short f2bf(float f) {
    unsigned u = __float_as_uint(f);
    unsigned r = (u + 0x7fffu + ((u >> 16) & 1u)) >> 16;   // RNE
    return (short)r;
}

__device__ __forceinline__ bf16x8 pack8(f32x4 a, f32x4 b) {
    bf16x8 r;
    r[0] = f2bf(a[0]); r[1] = f2bf(a[1]); r[2] = f2bf(a[2]); r[3] = f2bf(a[3]);
    r[4] = f2bf(b[0]); r[5] = f2bf(b[1]); r[6] = f2bf(b[2]); r[7] = f2bf(b[3]);
    return r;
}

__global__ __launch_bounds__(256, 3) void band_attn_v4(
    const float* __restrict__ Q,
    const float* __restrict__ K,
    const float* __restrict__ V,
    float* __restrict__ ctx_out,   // [BH, S, DK]
    float* __restrict__ attn_out)  // [BH, S, S]
{
    __shared__ __align__(16) float Ps[TQ * PSTR];   // 41472 B -> 3 blocks/CU

    const int tid  = threadIdx.x;
    const int bh   = blockIdx.x >> 6;            // 64 tiles per head
    const int q0   = (blockIdx.x & 63) * TQ;
    const int base = q0 - 128;                   // kg = base + kl

    const int lane = tid & 63;
    const int wv   = tid >> 6;
    const int col  = lane & 15;
    const int quad = lane >> 4;

    const float* Qh = Q + ((size_t)bh * S_LEN + q0) * DK;
    const float* Kh = K + (size_t)bh * S_LEN * DK;
    const float* Vh = V + (size_t)bh * S_LEN * DK;

    // ---- Q A-frags, loaded once (pre-scaled by 1/8) ----
    bf16x8 qf[2][2];
    #pragma unroll
    for (int qt = 0; qt < 2; ++qt)
        #pragma unroll
        for (int h = 0; h < 2; ++h) {
            const float* qp = Qh + (size_t)(16 * qt + col) * DK + 32 * h + 8 * quad;
            f32x4 a = *(const f32x4*)qp;
            f32x4 b = *(const f32x4*)(qp + 4);
            a *= 0.125f; b *= 0.125f;
            qf[qt][h] = pack8(a, b);
        }

    // ---- score phase: B-frags straight from global K ----
    #pragma unroll
    for (int c = 0; c < NCH; ++c) {
        const int kl  = c * 64 + 16 * wv + col;          // this lane's key (klocal)
        const int kg  = base + kl;
        const int kgc = min(max(kg, 0), S_LEN - 1);      // clamp; mask fixes OOB
        bf16x8 kf[2];
        #pragma unroll
        for (int h = 0; h < 2; ++h) {
            const float* kp = Kh + (size_t)kgc * DK + 32 * h + 8 * quad;
            kf[h] = pack8(*(const f32x4*)kp, *(const f32x4*)(kp + 4));
        }
        #pragma unroll
        for (int qt = 0; qt < 2; ++qt) {
            f32x4 acc = {0.f, 0.f, 0.f, 0.f};
            acc = __builtin_amdgcn_mfma_f32_16x16x32_bf16(qf[qt][0], kf[0], acc, 0, 0, 0);
            acc = __builtin_amdgcn_mfma_f32_16x16x32_bf16(qf[qt][1], kf[1], acc, 0, 0, 0);
            #pragma unroll
            for (int r = 0; r < 4; ++r) {
                const int qloc = 16 * qt + quad * 4 + r;
                const bool ok = ((unsigned)kg < S_LEN) && (kl > qloc) && (kl <= qloc + 255);
                Ps[qloc * PSTR + kl] = ok ? acc[r] : -INFINITY;
            }
        }
    }
    __syncthreads();

    // ---- softmax: wave wv owns rows 8wv..8wv+7 (320 = 5*64 per row) ----
    #pragma unroll
    for (int rr = 0; rr < 8; ++rr) {
        float* row = Ps + (wv * 8 + rr) * PSTR;
        float v[5];
        #pragma unroll
        for (int j = 0; j < 5; ++j) v[j] = row[lane + 64 * j];
        float m = fmaxf(fmaxf(fmaxf(v[0], v[1]), fmaxf(v[2], v[3])), v[4]);
        #pragma unroll
        for (int off = 32; off > 0; off >>= 1) m = fmaxf(m, __shfl_xor(m, off, 64));
        float e[5], sum = 0.f;
        #pragma unroll
        for (int j = 0; j < 5; ++j) { e[j] = __expf(v[j] - m); sum += e[j]; }
        #pragma unroll
        for (int off = 32; off > 0; off >>= 1) sum += __shfl_xor(sum, off, 64);
        const float inv = 1.0f / sum;
        #pragma unroll
        for (int j = 0; j < 5; ++j) row[lane + 64 * j] = e[j] * inv;
    }
    __syncthreads();   // Ps probs visible to all waves (last barrier)

    // ---- PV phase: A from Ps (LDS), B straight from global V (d = 16wv+col) ----
    f32x4 o0 = {0.f, 0.f, 0.f, 0.f}, o1 = {0.f, 0.f, 0.f, 0.f};
    const float* vcol = Vh + 16 * wv + col;
    #pragma unroll
    for (int c = 0; c < NCH; ++c) {
        #pragma unroll
        for (int h = 0; h < 2; ++h) {
            const int k0 = base + c * 64 + 32 * h + 8 * quad;
            f32x4 va, vb;
            #pragma unroll
            for (int j = 0; j < 4; ++j) {
                int kgc = min(max(k0 + j, 0), S_LEN - 1);
                va[j] = vcol[(size_t)kgc * DK];
            }
            #pragma unroll
            for (int j = 0; j < 4; ++j) {
                int kgc = min(max(k0 + 4 + j, 0), S_LEN - 1);
                vb[j] = vcol[(size_t)kgc * DK];
            }
            bf16x8 vf = pack8(va, vb);
            #pragma unroll
            for (int qt = 0; qt < 2; ++qt) {
                const float* pp = Ps + (size_t)(16 * qt + col) * PSTR + c * 64 + 32 * h + 8 * quad;
                bf16x8 pf = pack8(*(const f32x4*)pp, *(const f32x4*)(pp + 4));
                if (qt == 0) o0 = __builtin_amdgcn_mfma_f32_16x16x32_bf16(pf, vf, o0, 0, 0, 0);
                else         o1 = __builtin_amdgcn_mfma_f32_16x16x32_bf16(pf, vf, o1, 0, 0, 0);
            }
        }
    }

    // ---- ctx write ----
    {
        float* Cg = ctx_out + ((size_t)bh * S_LEN + q0) * DK;
        #pragma unroll
        for (int r = 0; r < 4; ++r) {
            Cg[(size_t)(quad * 4 + r) * DK + 16 * wv + col]      = o0[r];
            Cg[(size_t)(16 + quad * 4 + r) * DK + 16 * wv + col] = o1[r];
        }
    }

    // ---- attn write: full rows (band + zeros), wave-private rows, no barrier after ----
    {
        const int kloff4 = (q0 >> 2) - 32;       // (base)/4, may be negative
        f32x4* A4 = (f32x4*)(attn_out + ((size_t)bh * S_LEN + q0 + 8 * wv) * S_LEN);
        const f32x4* Ps4 = (const f32x4*)Ps;
        const f32x4 z = {0.f, 0.f, 0.f, 0.f};
        #pragma unroll 8
        for (int i = 0; i < 64; ++i) {
            const int idx  = i * 64 + lane;      // 4096 f32x4 per wave
            const int r    = idx >> 9;           // 0..7 (uniform per instr)
            const int slot = idx & 511;
            const int kl4  = slot - kloff4;
            f32x4 v = ((unsigned)kl4 < 80u) ? Ps4[(8 * wv + r) * PSTR4 + kl4] : z;
            A4[(size_t)r * 512 + slot] = v;
        }
    }
}

extern "C" void kernel_launch(void* const* d_in, const int* in_sizes, int n_in,
                              void* d_out, int out_size, void* d_ws, size_t ws_size,
                              hipStream_t stream) {
    const float* Q = (const float*)d_in[0];
    const float* K = (const float*)d_in[1];
    const float* V = (const float*)d_in[2];
    float* out = (float*)d_out;

    const int BH = in_sizes[0] / (S_LEN * DK);          // B*H = 16
    const size_t ctx_elems = (size_t)BH * S_LEN * DK;
    float* ctx  = out;
    float* attn = out + ctx_elems;

    dim3 grid(BH * (S_LEN / TQ));                       // 1024 blocks
    band_attn_v4<<<grid, 256, 0, stream>>>(Q, K, V, ctx, attn);
}